// Round 1
// baseline (445.303 us; speedup 1.0000x reference)
//
#include <hip/hip_runtime.h>
#include <stdint.h>

// Problem: out = relu(A) * mask(top-64 per row), A: 8192x8192 fp32.
// One block per row; exact radix-select (4x 8-bit passes) of the K-th largest
// relu'd value per row; exact tie handling (lowest-index-first, as lax.top_k).

constexpr int N     = 8192;
constexpr int K     = 64;
constexpr int BLOCK = 256;
constexpr int VPT   = N / BLOCK;   // 32 values per thread (registers)
constexpr int V4    = VPT / 4;     // 8 float4 per thread
constexpr int EQ_CAP = 256;

__global__ __launch_bounds__(BLOCK) void topk_row_kernel(
    const float* __restrict__ A, float* __restrict__ out)
{
    __shared__ uint32_t hist[4][256];   // per-wave histogram copies
    __shared__ uint32_t s_prefix;       // accumulated threshold bit pattern
    __shared__ uint32_t s_k;            // remaining rank within current prefix
    __shared__ uint32_t s_cnt;          // count of elements == T
    __shared__ int      s_tzero;        // <K positive elements in row
    __shared__ uint32_t s_eq[EQ_CAP];   // indices of elements == T

    const int tid  = threadIdx.x;
    const int wave = tid >> 6;
    const int lane = tid & 63;
    const int row  = blockIdx.x;

    const float4* rowp = reinterpret_cast<const float4*>(A + (size_t)row * N);
    float4*       outp = reinterpret_cast<float4*>(out + (size_t)row * N);

    // ---- load + relu into registers (bit patterns; uint order == float order for >=0) ----
    uint32_t v[VPT];
    #pragma unroll
    for (int j = 0; j < V4; ++j) {
        float4 f = rowp[tid + j * BLOCK];
        v[4*j+0] = (f.x > 0.f) ? __float_as_uint(f.x) : 0u;
        v[4*j+1] = (f.y > 0.f) ? __float_as_uint(f.y) : 0u;
        v[4*j+2] = (f.z > 0.f) ? __float_as_uint(f.z) : 0u;
        v[4*j+3] = (f.w > 0.f) ? __float_as_uint(f.w) : 0u;
    }

    // ---- init ----
    #pragma unroll
    for (int j = 0; j < 4; ++j) hist[j][tid] = 0;
    if (tid == 0) { s_prefix = 0; s_k = K; s_cnt = 0; s_tzero = 0; }
    __syncthreads();

    // ---- pass 1: top byte; skip zeros (avoid same-address atomic storm on bin 0) ----
    #pragma unroll
    for (int j = 0; j < VPT; ++j) {
        uint32_t x = v[j];
        if (x) atomicAdd(&hist[wave][x >> 24], 1u);
    }
    __syncthreads();
    {
        uint32_t tot = hist[0][tid] + hist[1][tid] + hist[2][tid] + hist[3][tid];
        hist[0][tid] = tot;   // each thread touches only its own bin: no hazard
    }
    __syncthreads();

    // scan (wave 0): find max bin b with suffix-count S(b) >= k
    if (wave == 0) {
        uint32_t k  = s_k;
        uint32_t h0 = hist[0][4*lane+0];
        uint32_t h1 = hist[0][4*lane+1];
        uint32_t h2 = hist[0][4*lane+2];
        uint32_t h3 = hist[0][4*lane+3];
        uint32_t suf = h0 + h1 + h2 + h3;
        #pragma unroll
        for (int d = 1; d < 64; d <<= 1) {
            uint32_t o = __shfl_down(suf, d, 64);
            if (lane + d < 64) suf += o;
        }
        unsigned long long m = __ballot(suf >= k);
        if (m == 0ull) {
            if (lane == 0) s_tzero = 1;   // fewer than K positives: T = 0
        } else {
            int cl = 63 - __builtin_clzll(m);  // highest lane whose range contains b
            if (lane == cl) {
                uint32_t S0 = suf;       // S at bin 4*lane
                uint32_t S1 = S0 - h0;
                uint32_t S2 = S1 - h1;
                uint32_t S3 = S2 - h2;
                int b; uint32_t Sb, hb;
                if      (S3 >= k) { b = 4*lane+3; Sb = S3; hb = h3; }
                else if (S2 >= k) { b = 4*lane+2; Sb = S2; hb = h2; }
                else if (S1 >= k) { b = 4*lane+1; Sb = S1; hb = h1; }
                else              { b = 4*lane+0; Sb = S0; hb = h0; }
                s_prefix |= (uint32_t)b << 24;
                s_k = k - (Sb - hb);     // subtract count strictly greater at this level
            }
        }
    }
    __syncthreads();

    if (s_tzero) {
        // < K positive entries: mask keeps all positives (zeros stay zero either way)
        #pragma unroll
        for (int j = 0; j < V4; ++j) {
            float4 o;
            o.x = __uint_as_float(v[4*j+0]);
            o.y = __uint_as_float(v[4*j+1]);
            o.z = __uint_as_float(v[4*j+2]);
            o.w = __uint_as_float(v[4*j+3]);
            outp[tid + j * BLOCK] = o;
        }
        return;
    }

    // ---- passes 2..4: refine bytes 2,1,0 among prefix-matching candidates ----
    for (int shift = 16; shift >= 0; shift -= 8) {
        uint32_t prefix = s_prefix;
        #pragma unroll
        for (int j = 0; j < 4; ++j) hist[j][tid] = 0;
        __syncthreads();

        const uint32_t himask = 0xFFFFFFFFu << (shift + 8);
        #pragma unroll
        for (int j = 0; j < VPT; ++j) {
            uint32_t x = v[j];
            if ((x & himask) == prefix)
                atomicAdd(&hist[wave][(x >> shift) & 255u], 1u);
        }
        __syncthreads();
        {
            uint32_t tot = hist[0][tid] + hist[1][tid] + hist[2][tid] + hist[3][tid];
            hist[0][tid] = tot;
        }
        __syncthreads();

        if (wave == 0) {
            uint32_t k  = s_k;
            uint32_t h0 = hist[0][4*lane+0];
            uint32_t h1 = hist[0][4*lane+1];
            uint32_t h2 = hist[0][4*lane+2];
            uint32_t h3 = hist[0][4*lane+3];
            uint32_t suf = h0 + h1 + h2 + h3;
            #pragma unroll
            for (int d = 1; d < 64; d <<= 1) {
                uint32_t o = __shfl_down(suf, d, 64);
                if (lane + d < 64) suf += o;
            }
            unsigned long long m = __ballot(suf >= k);
            int cl = 63 - __builtin_clzll(m);   // m != 0 guaranteed here
            if (lane == cl) {
                uint32_t S0 = suf;
                uint32_t S1 = S0 - h0;
                uint32_t S2 = S1 - h1;
                uint32_t S3 = S2 - h2;
                int b; uint32_t Sb, hb;
                if      (S3 >= k) { b = 4*lane+3; Sb = S3; hb = h3; }
                else if (S2 >= k) { b = 4*lane+2; Sb = S2; hb = h2; }
                else if (S1 >= k) { b = 4*lane+1; Sb = S1; hb = h1; }
                else              { b = 4*lane+0; Sb = S0; hb = h0; }
                s_prefix |= (uint32_t)b << shift;
                s_k = k - (Sb - hb);
            }
        }
        __syncthreads();
    }

    // ---- output: keep x > T; among x == T keep the `need` lowest indices ----
    const uint32_t T    = s_prefix;        // exact bit pattern of K-th largest
    const uint32_t need = s_k;             // #elements equal to T to keep (>=1)
    const float    Tf   = __uint_as_float(T);

    #pragma unroll
    for (int j = 0; j < V4; ++j) {
        const int base = (tid + j * BLOCK) * 4;
        float4 o;
        float* oc = &o.x;
        #pragma unroll
        for (int c = 0; c < 4; ++c) {
            uint32_t x = v[4*j+c];
            float val = 0.f;
            if (x > T) {
                val = __uint_as_float(x);
            } else if (x == T) {
                uint32_t p = atomicAdd(&s_cnt, 1u);
                if (p < EQ_CAP) s_eq[p] = (uint32_t)(base + c);
            }
            oc[c] = val;
        }
        outp[tid + j * BLOCK] = o;
    }
    __syncthreads();

    if (tid == 0) {
        uint32_t cnt = s_cnt < (uint32_t)EQ_CAP ? s_cnt : (uint32_t)EQ_CAP;
        for (uint32_t n = 0; n < need; ++n) {   // need is typically 1
            uint32_t best = 0xFFFFFFFFu, bi = 0;
            for (uint32_t i = 0; i < cnt; ++i) {
                if (s_eq[i] < best) { best = s_eq[i]; bi = i; }
            }
            if (best != 0xFFFFFFFFu) {
                s_eq[bi] = 0xFFFFFFFFu;
                out[(size_t)row * N + best] = Tf;
            }
        }
    }
}

extern "C" void kernel_launch(void* const* d_in, const int* in_sizes, int n_in,
                              void* d_out, int out_size, void* d_ws, size_t ws_size,
                              hipStream_t stream) {
    const float* A = (const float*)d_in[0];   // 8192*8192 fp32
    // d_in[1] (idx) is unused by the reference.
    float* out = (float*)d_out;
    topk_row_kernel<<<N, BLOCK, 0, stream>>>(A, out);
}

// Round 2
// 442.921 us; speedup vs baseline: 1.0054x; 1.0054x over previous
//
#include <hip/hip_runtime.h>
#include <stdint.h>

// out = relu(A) * mask(top-64 per row), A: 8192x8192 fp32. Exact (bit-exact
// threshold + lowest-index-first tie handling, matching lax.top_k + scatter).
//
// One block per row. Strategy: values stay in registers (32/thread).
//  1) row max -> exponent window count (register counters, no LDS atomics)
//  2) compact ~190 candidates (top exponent binades) into LDS list
//  3) exact 4x8-bit radix select of the 64th-largest bit pattern over the list
//  4) write relu(A) masked by threshold; exact tie fixup
// Cold-path fallbacks (never taken for normal data) keep it exact for any input.

constexpr int N      = 8192;
constexpr int K      = 64;
constexpr int BLOCK  = 256;
constexpr int VPT    = N / BLOCK;   // 32 values/thread in registers
constexpr int V4     = VPT / 4;     // 8 float4 per thread
constexpr int CAP    = 1536;        // candidate list capacity
constexpr int EQ_CAP = 256;

__device__ __forceinline__ uint32_t wave_reduce_add(uint32_t x) {
    #pragma unroll
    for (int d = 32; d >= 1; d >>= 1) x += __shfl_down(x, d, 64);
    return x;   // valid in lane 0
}

// wave 0 only: hist256 holds 256 summed bins; pick digit at `shift`.
__device__ __forceinline__ void scan_pick(const uint32_t* hist256,
                                          uint32_t* s_prefix, uint32_t* s_k,
                                          int shift, int lane) {
    uint32_t k  = *s_k;
    uint32_t h0 = hist256[4 * lane + 0];
    uint32_t h1 = hist256[4 * lane + 1];
    uint32_t h2 = hist256[4 * lane + 2];
    uint32_t h3 = hist256[4 * lane + 3];
    uint32_t suf = h0 + h1 + h2 + h3;
    #pragma unroll
    for (int d = 1; d < 64; d <<= 1) {          // suffix sum across lanes
        uint32_t o = __shfl_down(suf, d, 64);
        if (lane + d < 64) suf += o;
    }
    unsigned long long m = __ballot(suf >= k);  // nonzero by invariant
    int cl = 63 - __builtin_clzll(m);
    if (lane == cl) {
        uint32_t S0 = suf, S1 = S0 - h0, S2 = S1 - h1, S3 = S2 - h2;
        int b; uint32_t Sb, hb;
        if      (S3 >= k) { b = 3; Sb = S3; hb = h3; }
        else if (S2 >= k) { b = 2; Sb = S2; hb = h2; }
        else if (S1 >= k) { b = 1; Sb = S1; hb = h1; }
        else              { b = 0; Sb = S0; hb = h0; }
        *s_prefix |= (uint32_t)(4 * lane + b) << shift;
        *s_k = k - (Sb - hb);                   // strictly-greater removed
    }
}

__global__ __launch_bounds__(BLOCK) void topk_row_kernel(
    const float* __restrict__ A, float* __restrict__ out)
{
    __shared__ uint32_t hist[4][256];     // per-wave histogram copies (radix)
    __shared__ uint32_t list[CAP];        // candidate bit patterns
    __shared__ uint32_t s_eq[EQ_CAP];     // indices of elements == T
    __shared__ uint32_t s_rb[4][5];       // cross-wave reduce scratch
    __shared__ uint32_t s_rmax[4];
    __shared__ uint32_t s_prefix, s_k, s_cnt, s_listcnt, s_C, s_ecut, s_mode, s_max;

    const int tid  = threadIdx.x;
    const int wave = tid >> 6;
    const int lane = tid & 63;
    const int row  = blockIdx.x;

    const float4* rowp = reinterpret_cast<const float4*>(A + (size_t)row * N);
    float4*       outp = reinterpret_cast<float4*>(out + (size_t)row * N);

    // ---- load + relu into registers (uint order == float order for >= 0) ----
    uint32_t v[VPT];
    #pragma unroll
    for (int j = 0; j < V4; ++j) {
        float4 f = rowp[tid + j * BLOCK];
        v[4*j+0] = (f.x > 0.f) ? __float_as_uint(f.x) : 0u;
        v[4*j+1] = (f.y > 0.f) ? __float_as_uint(f.y) : 0u;
        v[4*j+2] = (f.z > 0.f) ? __float_as_uint(f.z) : 0u;
        v[4*j+3] = (f.w > 0.f) ? __float_as_uint(f.w) : 0u;
    }
    if (tid == 0) { s_listcnt = 0; s_cnt = 0; }

    // ---- row max (registers + shuffles; no contended LDS) ----
    uint32_t mx = 0;
    #pragma unroll
    for (int j = 0; j < VPT; ++j) mx = (v[j] > mx) ? v[j] : mx;
    #pragma unroll
    for (int d = 32; d >= 1; d >>= 1) {
        uint32_t o = __shfl_down(mx, d, 64);
        mx = (o > mx) ? o : mx;
    }
    if (lane == 0) s_rmax[wave] = mx;
    __syncthreads();
    if (tid == 0) {
        uint32_t m = s_rmax[0];
        m = (s_rmax[1] > m) ? s_rmax[1] : m;
        m = (s_rmax[2] > m) ? s_rmax[2] : m;
        m = (s_rmax[3] > m) ? s_rmax[3] : m;
        s_max = m;
    }
    __syncthreads();
    const uint32_t expM = s_max >> 23;

    // ---- 4-bin exponent window + positive count (register counters) ----
    uint32_t b0 = 0, b1 = 0, b2 = 0, b3 = 0, cpos = 0;
    #pragma unroll
    for (int j = 0; j < VPT; ++j) {
        uint32_t x = v[j];
        if (x != 0u) {
            uint32_t d = expM - (x >> 23);
            cpos += 1u;
            b0 += (d == 0u); b1 += (d == 1u); b2 += (d == 2u); b3 += (d == 3u);
        }
    }
    b0 = wave_reduce_add(b0); b1 = wave_reduce_add(b1);
    b2 = wave_reduce_add(b2); b3 = wave_reduce_add(b3);
    cpos = wave_reduce_add(cpos);
    if (lane == 0) {
        s_rb[wave][0] = b0; s_rb[wave][1] = b1; s_rb[wave][2] = b2;
        s_rb[wave][3] = b3; s_rb[wave][4] = cpos;
    }
    __syncthreads();
    if (tid == 0) {
        uint32_t B[5];
        #pragma unroll
        for (int c = 0; c < 5; ++c)
            B[c] = s_rb[0][c] + s_rb[1][c] + s_rb[2][c] + s_rb[3][c];
        if (B[4] < (uint32_t)K) {
            s_mode = 1;                       // < K positives: out = relu(A)
        } else {
            s_mode = 0;
            uint32_t cum = 0; int jf = -1;
            #pragma unroll
            for (int j = 0; j < 4; ++j) {
                cum += B[j];
                if (jf < 0 && cum >= (uint32_t)K) jf = j;
            }
            if (jf >= 0) {
                uint32_t c2 = 0;
                for (int j = 0; j <= jf; ++j) c2 += B[j];
                s_C = c2; s_ecut = expM - (uint32_t)jf;
            } else {
                s_C = 0;                      // window too small: widen below
            }
        }
    }
    __syncthreads();

    if (s_mode == 1) {                        // pass-through path
        #pragma unroll
        for (int j = 0; j < V4; ++j) {
            float4 o;
            o.x = __uint_as_float(v[4*j+0]); o.y = __uint_as_float(v[4*j+1]);
            o.z = __uint_as_float(v[4*j+2]); o.w = __uint_as_float(v[4*j+3]);
            outp[tid + j * BLOCK] = o;
        }
        return;
    }

    if (s_C == 0) {                           // cold: widen exponent window
        uint32_t ecut = (expM > 7u) ? (expM - 7u) : 0u;
        for (;;) {
            __syncthreads();                  // WAR guard on s_C
            uint32_t lc = 0;
            #pragma unroll
            for (int j = 0; j < VPT; ++j)
                lc += (v[j] != 0u && (v[j] >> 23) >= ecut) ? 1u : 0u;
            lc = wave_reduce_add(lc);
            if (lane == 0) s_rb[wave][0] = lc;
            __syncthreads();
            if (tid == 0) {
                s_C = s_rb[0][0] + s_rb[1][0] + s_rb[2][0] + s_rb[3][0];
                s_ecut = ecut;
            }
            __syncthreads();
            if (s_C >= (uint32_t)K || ecut == 0u) break;
            ecut = (ecut > 4u) ? (ecut - 4u) : 0u;
        }
    }
    __syncthreads();
    const uint32_t C    = s_C;
    const uint32_t ecut = s_ecut;

    // ---- init radix state ----
    #pragma unroll
    for (int c = 0; c < 4; ++c) hist[c][tid] = 0;
    if (tid == 0) { s_prefix = 0; s_k = K; }
    __syncthreads();

    if (C <= (uint32_t)CAP) {
        // ---- hot path: compact candidates, radix-select over small list ----
        uint32_t lc = 0;
        #pragma unroll
        for (int j = 0; j < VPT; ++j)
            lc += (v[j] != 0u && (v[j] >> 23) >= ecut) ? 1u : 0u;
        uint32_t incl = lc;
        #pragma unroll
        for (int d = 1; d < 64; d <<= 1) {
            uint32_t t = __shfl_up(incl, d, 64);
            if (lane >= d) incl += t;
        }
        uint32_t baseV = 0;
        if (lane == 63) baseV = atomicAdd(&s_listcnt, incl);  // 1 atomic/wave
        uint32_t base = __shfl(baseV, 63, 64);
        uint32_t pos  = base + (incl - lc);
        #pragma unroll
        for (int j = 0; j < VPT; ++j) {
            uint32_t x = v[j];
            if (x != 0u && (x >> 23) >= ecut) list[pos++] = x;
        }
        __syncthreads();

        // pass 1: top byte over list (~C/256 elems/thread)
        for (uint32_t i = tid; i < C; i += BLOCK)
            atomicAdd(&hist[wave][list[i] >> 24], 1u);
        __syncthreads();
        hist[0][tid] = hist[0][tid] + hist[1][tid] + hist[2][tid] + hist[3][tid];
        __syncthreads();
        if (wave == 0) scan_pick(hist[0], &s_prefix, &s_k, 24, lane);
        __syncthreads();

        for (int shift = 16; shift >= 0; shift -= 8) {
            const uint32_t prefix = s_prefix;
            #pragma unroll
            for (int c = 0; c < 4; ++c) hist[c][tid] = 0;
            __syncthreads();
            const uint32_t himask = 0xFFFFFFFFu << (shift + 8);
            for (uint32_t i = tid; i < C; i += BLOCK) {
                uint32_t x = list[i];
                if ((x & himask) == prefix)
                    atomicAdd(&hist[wave][(x >> shift) & 255u], 1u);
            }
            __syncthreads();
            hist[0][tid] = hist[0][tid] + hist[1][tid] + hist[2][tid] + hist[3][tid];
            __syncthreads();
            if (wave == 0) scan_pick(hist[0], &s_prefix, &s_k, shift, lane);
            __syncthreads();
        }
    } else {
        // ---- cold path: full-register radix (exact, contended, rare) ----
        #pragma unroll
        for (int j = 0; j < VPT; ++j) {
            uint32_t x = v[j];
            if (x) atomicAdd(&hist[wave][x >> 24], 1u);
        }
        __syncthreads();
        hist[0][tid] = hist[0][tid] + hist[1][tid] + hist[2][tid] + hist[3][tid];
        __syncthreads();
        if (wave == 0) scan_pick(hist[0], &s_prefix, &s_k, 24, lane);
        __syncthreads();

        for (int shift = 16; shift >= 0; shift -= 8) {
            const uint32_t prefix = s_prefix;
            #pragma unroll
            for (int c = 0; c < 4; ++c) hist[c][tid] = 0;
            __syncthreads();
            const uint32_t himask = 0xFFFFFFFFu << (shift + 8);
            #pragma unroll
            for (int j = 0; j < VPT; ++j) {
                uint32_t x = v[j];
                if ((x & himask) == prefix)
                    atomicAdd(&hist[wave][(x >> shift) & 255u], 1u);
            }
            __syncthreads();
            hist[0][tid] = hist[0][tid] + hist[1][tid] + hist[2][tid] + hist[3][tid];
            __syncthreads();
            if (wave == 0) scan_pick(hist[0], &s_prefix, &s_k, shift, lane);
            __syncthreads();
        }
    }

    // ---- output: keep x > T; among x == T keep `need` lowest indices ----
    const uint32_t T    = s_prefix;   // exact bit pattern of K-th largest
    const uint32_t need = s_k;        // #elements == T inside top-K (>= 1)
    const float    Tf   = __uint_as_float(T);

    #pragma unroll
    for (int j = 0; j < V4; ++j) {
        const int base = (tid + j * BLOCK) * 4;
        float4 o;
        float* oc = &o.x;
        #pragma unroll
        for (int c = 0; c < 4; ++c) {
            uint32_t x = v[4*j+c];
            float val = 0.f;
            if (x > T) {
                val = __uint_as_float(x);
            } else if (x == T) {
                uint32_t p = atomicAdd(&s_cnt, 1u);
                if (p < (uint32_t)EQ_CAP) s_eq[p] = (uint32_t)(base + c);
            }
            oc[c] = val;
        }
        outp[tid + j * BLOCK] = o;
    }
    __syncthreads();

    if (tid == 0) {
        uint32_t cnt = s_cnt < (uint32_t)EQ_CAP ? s_cnt : (uint32_t)EQ_CAP;
        for (uint32_t n = 0; n < need; ++n) {     // need is typically 1
            uint32_t best = 0xFFFFFFFFu, bi = 0;
            for (uint32_t i = 0; i < cnt; ++i)
                if (s_eq[i] < best) { best = s_eq[i]; bi = i; }
            if (best != 0xFFFFFFFFu) {
                s_eq[bi] = 0xFFFFFFFFu;
                out[(size_t)row * N + best] = Tf;
            }
        }
    }
}

extern "C" void kernel_launch(void* const* d_in, const int* in_sizes, int n_in,
                              void* d_out, int out_size, void* d_ws, size_t ws_size,
                              hipStream_t stream) {
    const float* A = (const float*)d_in[0];   // 8192*8192 fp32
    // d_in[1] (idx) is unused by the reference.
    float* out = (float*)d_out;
    topk_row_kernel<<<N, BLOCK, 0, stream>>>(A, out);
}